// Round 1
// baseline (147.799 us; speedup 1.0000x reference)
//
#include <hip/hip_runtime.h>

// Deformable Conv1d, constrained sampling (U in {t,t+1,t+2} -> 4-tap window).
// Shapes: x[16][128][4096] f32, offsets[16][1][4094][3], mask[16][3][4094],
//         weight[128][128][3], bias[128] -> out[16][128][4094]
#define BB 16
#define CI 128
#define CO 128
#define LL 4096
#define LOUT 4094
#define KK 3
#define TT 128           // t-tile per block
#define CT 16            // c-tile per GEMM stage
#define NCT (CI / CT)    // 8
#define NTILE 32         // ceil(4094/128)
#define WPAD 49          // w_lds row pad (48+1)

__global__ __launch_bounds__(256, 2)
void dconv1d_f32_kernel(const float* __restrict__ x,
                        const float* __restrict__ offs,
                        const float* __restrict__ mask,
                        const float* __restrict__ w,
                        const float* __restrict__ bias,
                        float* __restrict__ out) {
    __shared__ float coef[KK][4][TT];        // 6 KB   (per-(t,k) 4-tap coeffs)
    __shared__ float w_lds[CO][WPAD];        // 24.5 KB (w[o][cc*3+k] for c-tile)
    __shared__ float xs_lds[CT * KK][TT];    // 24 KB  (sampled+masked x)

    const int bid  = blockIdx.x;
    const int b    = bid >> 5;        // / NTILE
    const int tile = bid & (NTILE - 1);
    const int t0   = tile * TT;
    const int tid  = threadIdx.x;

    // ---- phase 0: per-(t,k) 4-tap coefficients (exact reference fp32 order) ----
    for (int e = tid; e < KK * TT; e += 256) {
        const int t  = e & (TT - 1);
        const int k  = e >> 7;
        const int gt = t0 + t;
        float c0 = 0.f, c1 = 0.f, c2 = 0.f, c3 = 0.f;
        if (gt < LOUT) {
            const float off = offs[(b * LOUT + gt) * KK + k];
            const float m   = mask[(b * KK + k) * LOUT + gt];
            const float gtf = (float)gt;
            float T = (gtf + (float)k) + off;          // t0s + dil_pos + offsets
            T = fminf(fmaxf(T, gtf), gtf + 2.0f);      // clamp to receptive field
            int U = (int)floorf(T);
            if (U > LL - 2) U = LL - 2;                // clip(., 0, l-2); lower is free (T>=gt>=0)
            const float Uf = (float)U;
            const float G0 = fmaxf(0.f, 1.f - fabsf(Uf - T)) * m;
            const float G1 = fmaxf(0.f, 1.f - fabsf(Uf + 1.f - T)) * m;
            const int d0 = U - gt;                     // 0..2
            c0 = (d0 == 0) ? G0 : 0.f;
            c1 = (d0 == 0) ? G1 : ((d0 == 1) ? G0 : 0.f);
            c2 = (d0 == 1) ? G1 : ((d0 == 2) ? G0 : 0.f);
            c3 = (d0 == 2) ? G1 : 0.f;
        }
        coef[k][0][t] = c0;
        coef[k][1][t] = c1;
        coef[k][2][t] = c2;
        coef[k][3][t] = c3;
    }

    float acc[8][8];
#pragma unroll
    for (int i = 0; i < 8; ++i)
#pragma unroll
        for (int j = 0; j < 8; ++j) acc[i][j] = 0.f;

    __syncthreads();

    const int og = tid & 15;   // output-channel group (o = og + 16*i)
    const int tg = tid >> 4;   // t group (gt = t0 + tg*8 + j)

    for (int ct = 0; ct < NCT; ++ct) {
        if (ct) __syncthreads();  // previous GEMM reads done before overwrite

        // ---- stage w tile: w_lds[o][cc*3+k], coalesced 48-float runs ----
        for (int e = tid; e < CO * 48; e += 256) {
            const int kc = e % 48;
            const int o  = e / 48;
            w_lds[o][kc] = w[o * (CI * KK) + ct * (CT * KK) + kc];
        }

        // ---- build xs tile: xs_lds[cc*3+k][t] = sum_d coef[k][d][t]*x[c, t0+t+d] ----
        for (int e = tid; e < CT * KK * TT; e += 256) {
            const int t  = e & (TT - 1);
            const int r  = e >> 7;          // 0..47
            const int k  = r % 3;
            const int cc = r / 3;
            const float* xrow = x + (size_t)(b * CI + ct * CT + cc) * LL + t0 + t;
            const int base = t0 + t;        // <= 4095 always
            const float x0 = xrow[0];
            const float x1 = (base + 1 < LL) ? xrow[1] : 0.f;
            const float x2 = (base + 2 < LL) ? xrow[2] : 0.f;
            const float x3 = (base + 3 < LL) ? xrow[3] : 0.f;
            xs_lds[cc * KK + k][t] = coef[k][0][t] * x0 + coef[k][1][t] * x1 +
                                     coef[k][2][t] * x2 + coef[k][3][t] * x3;
        }
        __syncthreads();

        // ---- register-blocked GEMM: 8 o x 8 t per thread ----
        for (int cc = 0; cc < CT; ++cc) {
            float wv[3][8], xv[3][8];
#pragma unroll
            for (int k2 = 0; k2 < 3; ++k2)
#pragma unroll
                for (int i = 0; i < 8; ++i)
                    wv[k2][i] = w_lds[og + 16 * i][cc * 3 + k2];  // 16 distinct banks
#pragma unroll
            for (int k2 = 0; k2 < 3; ++k2)
#pragma unroll
                for (int j = 0; j < 8; ++j)
                    xv[k2][j] = xs_lds[cc * 3 + k2][tg * 8 + j];
#pragma unroll
            for (int i = 0; i < 8; ++i)
#pragma unroll
                for (int j = 0; j < 8; ++j) {
                    float s = acc[i][j];
                    s = fmaf(wv[0][i], xv[0][j], s);
                    s = fmaf(wv[1][i], xv[1][j], s);
                    s = fmaf(wv[2][i], xv[2][j], s);
                    acc[i][j] = s;
                }
        }
    }

    // ---- epilogue: bias + store ----
#pragma unroll
    for (int i = 0; i < 8; ++i) {
        const int o = og + 16 * i;
        const float bv = bias[o];
        float* orow = out + (size_t)(b * CO + o) * LOUT + t0 + tg * 8;
#pragma unroll
        for (int j = 0; j < 8; ++j) {
            const int gt = t0 + tg * 8 + j;
            if (gt < LOUT) orow[j] = acc[i][j] + bv;
        }
    }
}

extern "C" void kernel_launch(void* const* d_in, const int* in_sizes, int n_in,
                              void* d_out, int out_size, void* d_ws, size_t ws_size,
                              hipStream_t stream) {
    const float* x    = (const float*)d_in[0];
    const float* offs = (const float*)d_in[1];
    const float* mask = (const float*)d_in[2];
    const float* w    = (const float*)d_in[3];
    const float* bias = (const float*)d_in[4];
    float* out = (float*)d_out;

    dim3 grid(BB * NTILE);   // 512 blocks: b-major, 32 t-tiles each
    dim3 block(256);
    dconv1d_f32_kernel<<<grid, block, 0, stream>>>(x, offs, mask, w, bias, out);
}

// Round 2
// 64.670 us; speedup vs baseline: 2.2854x; 2.2854x over previous
//
#include <hip/hip_runtime.h>

// Deformable Conv1d via implicit GEMM on MFMA (bf16 in, fp32 acc).
// out[b,o,t] = sum_{ck} w[o][ck] * xs[b][ck][t],  ck = c*3+k,
// xs[ck][t] = mask[b,k,t] * (G0*x[b,c,U] + G1*x[b,c,U+1])  (constrained sampling)
#define BB 16
#define CI 128
#define CO 128
#define LL 4096
#define LOUT 4094
#define CK 384           // CI*3 = GEMM K
#define TT 64            // t-tile per block (GEMM N)
#define NTILE 64         // 64*64 = 4096 >= 4094

typedef short short8 __attribute__((ext_vector_type(8)));
typedef float floatx4 __attribute__((ext_vector_type(4)));

__device__ __forceinline__ ushort f2bf(float f) {   // RNE f32 -> bf16
    union { float f; uint u; } v; v.f = f;
    uint r = v.u + 0x7FFFu + ((v.u >> 16) & 1u);
    return (ushort)(r >> 16);
}

__global__ __launch_bounds__(256, 2)
void dconv1d_mfma_kernel(const float* __restrict__ x,
                         const float* __restrict__ offs,
                         const float* __restrict__ mask,
                         const float* __restrict__ w,
                         const float* __restrict__ bias,
                         float* __restrict__ out) {
    // xs tile: [t][ck] bf16, XOR-swizzled cols: col' = col ^ ((t&15)<<3). 49.2 KB.
    __shared__ ushort xs[TT][CK];

    const int tid  = threadIdx.x;
    const int lane = tid & 63;
    const int wv   = tid >> 6;          // wave 0..3 -> o-rows [wv*32, wv*32+32)
    const int bid  = blockIdx.x;
    const int b    = bid >> 6;          // / NTILE
    const int t0   = (bid & (NTILE - 1)) * TT;

    // ---- A fragments: w[o][ck] -> registers, bf16. Layout (16x16x32):
    // lane holds A[row = lane&15][k = (lane>>4)*8 + j], j=0..7.
    short8 afrag[2][12];
    {
        const int arow = wv * 32 + (lane & 15);
        const int ack  = (lane >> 4) * 8;
#pragma unroll 4
        for (int mf = 0; mf < 2; ++mf) {
            const float* wp = w + (size_t)(arow + mf * 16) * CK + ack;
#pragma unroll 4
            for (int ks = 0; ks < 12; ++ks) {
                floatx4 v0 = *(const floatx4*)(wp + ks * 32);
                floatx4 v1 = *(const floatx4*)(wp + ks * 32 + 4);
                union { uint u[4]; short8 s; } r;
                r.u[0] = (uint)f2bf(v0[0]) | ((uint)f2bf(v0[1]) << 16);
                r.u[1] = (uint)f2bf(v0[2]) | ((uint)f2bf(v0[3]) << 16);
                r.u[2] = (uint)f2bf(v1[0]) | ((uint)f2bf(v1[1]) << 16);
                r.u[3] = (uint)f2bf(v1[2]) | ((uint)f2bf(v1[3]) << 16);
                afrag[mf][ks] = r.s;
            }
        }
    }

    // ---- build xs tile: unit = (t, c-group of 8). 1024 units / 256 threads. ----
    for (int it = 0; it < 4; ++it) {
        const int u  = tid + it * 256;
        const int t  = u & (TT - 1);
        const int cg = u >> 6;                 // 0..15
        const int gt = t0 + t;

        float g0[3], g1[3];
        int   U[3];
#pragma unroll
        for (int k = 0; k < 3; ++k) {
            float ofv = 0.f, mv = 0.f;
            if (gt < LOUT) {
                ofv = offs[((size_t)b * LOUT + gt) * 3 + k];
                mv  = mask[((size_t)b * 3 + k) * LOUT + gt];
            }
            const float gtf = (float)gt;
            float T = (gtf + (float)k) + ofv;          // exact ref op order
            T = fminf(fmaxf(T, gtf), gtf + 2.0f);      // clamp to receptive field
            int Ui = (int)floorf(T);
            if (Ui > LL - 2) Ui = LL - 2;
            const float Uf = (float)Ui;
            g0[k] = fmaxf(0.f, 1.f - fabsf(Uf - T)) * mv;
            g1[k] = fmaxf(0.f, 1.f - fabsf(Uf + 1.f - T)) * mv;
            U[k] = Ui;
        }

        ushort vals[24];
#pragma unroll
        for (int ci = 0; ci < 8; ++ci) {
            const float* xr = x + ((size_t)b * CI + cg * 8 + ci) * LL;
#pragma unroll
            for (int k = 0; k < 3; ++k) {
                const float x0 = xr[U[k]];
                const float x1 = xr[U[k] + 1];         // U <= LL-2 -> in bounds
                vals[ci * 3 + k] = f2bf(g0[k] * x0 + g1[k] * x1);
            }
        }
        uint dw[12];
#pragma unroll
        for (int j = 0; j < 12; ++j)
            dw[j] = (uint)vals[2 * j] | ((uint)vals[2 * j + 1] << 16);
        const int swz = (t & 15) << 3;
#pragma unroll
        for (int j = 0; j < 3; ++j) {
            const int col = (cg * 24 + j * 8) ^ swz;   // 8-aligned, bijective
            uint4 q; q.x = dw[4*j]; q.y = dw[4*j+1]; q.z = dw[4*j+2]; q.w = dw[4*j+3];
            *(uint4*)(&xs[t][col]) = q;
        }
    }
    __syncthreads();

    // ---- GEMM: acc[mf][nf] over 12 k-steps of 32 ----
    floatx4 zero4 = {0.f, 0.f, 0.f, 0.f};
    floatx4 acc[2][4];
#pragma unroll
    for (int mf = 0; mf < 2; ++mf)
#pragma unroll
        for (int nf = 0; nf < 4; ++nf) acc[mf][nf] = zero4;

    const int bswz = (lane & 15) << 3;
#pragma unroll
    for (int ks = 0; ks < 12; ++ks) {
        short8 bfr[4];
#pragma unroll
        for (int nf = 0; nf < 4; ++nf) {
            const int tb  = nf * 16 + (lane & 15);     // B col = lane&15
            const int col = (ks * 32 + (lane >> 4) * 8) ^ bswz;
            bfr[nf] = *(const short8*)(&xs[tb][col]);
        }
#pragma unroll
        for (int mf = 0; mf < 2; ++mf)
#pragma unroll
            for (int nf = 0; nf < 4; ++nf)
                acc[mf][nf] = __builtin_amdgcn_mfma_f32_16x16x32_bf16(
                    afrag[mf][ks], bfr[nf], acc[mf][nf], 0, 0, 0);
    }

    // ---- epilogue: D col=lane&15 (t), row=(lane>>4)*4+reg (o). bias + store. ----
    float bv[2][4];
#pragma unroll
    for (int mf = 0; mf < 2; ++mf)
#pragma unroll
        for (int r = 0; r < 4; ++r)
            bv[mf][r] = bias[wv * 32 + mf * 16 + (lane >> 4) * 4 + r];

#pragma unroll
    for (int mf = 0; mf < 2; ++mf)
#pragma unroll
        for (int nf = 0; nf < 4; ++nf) {
            const int gt = t0 + nf * 16 + (lane & 15);
            if (gt < LOUT) {
#pragma unroll
                for (int r = 0; r < 4; ++r) {
                    const int o = wv * 32 + mf * 16 + (lane >> 4) * 4 + r;
                    out[((size_t)b * CO + o) * LOUT + gt] = acc[mf][nf][r] + bv[mf][r];
                }
            }
        }
}

extern "C" void kernel_launch(void* const* d_in, const int* in_sizes, int n_in,
                              void* d_out, int out_size, void* d_ws, size_t ws_size,
                              hipStream_t stream) {
    const float* x    = (const float*)d_in[0];
    const float* offs = (const float*)d_in[1];
    const float* mask = (const float*)d_in[2];
    const float* w    = (const float*)d_in[3];
    const float* bias = (const float*)d_in[4];
    float* out = (float*)d_out;

    dim3 grid(BB * NTILE);   // 1024 blocks
    dim3 block(256);
    dconv1d_mfma_kernel<<<grid, block, 0, stream>>>(x, offs, mask, w, bias, out);
}

// Round 3
// 64.157 us; speedup vs baseline: 2.3037x; 1.0080x over previous
//
#include <hip/hip_runtime.h>

// Deformable Conv1d via implicit GEMM on MFMA (bf16 in, fp32 acc).
// out[b,o,t] = sum_{ck} w[o][ck] * xs[b][ck][t],  ck = c*3+k,
// xs[ck][t] = mask[b,k,t] * (G0*x[b,c,U] + G1*x[b,c,U+1])  (constrained sampling)
// R3: LDS-staged epilogue with aligned float2 row-streaming (kills 4x write amp
//     + RMW fetch from LOUT=4094 row misalignment), 3 blocks/CU.
#define BB 16
#define CI 128
#define CO 128
#define LL 4096
#define LOUT 4094
#define CK 384           // CI*3 = GEMM K
#define TT 64            // t-tile per block (GEMM N)
#define NTILE 64         // 64*64 = 4096 >= 4094
#define OPAD 65          // obuf row stride (floats)

typedef short short8 __attribute__((ext_vector_type(8)));
typedef float floatx4 __attribute__((ext_vector_type(4)));

__device__ __forceinline__ ushort f2bf(float f) {   // RNE f32 -> bf16
    union { float f; uint u; } v; v.f = f;
    uint r = v.u + 0x7FFFu + ((v.u >> 16) & 1u);
    return (ushort)(r >> 16);
}

__global__ __launch_bounds__(256, 3)
void dconv1d_mfma_kernel(const float* __restrict__ x,
                         const float* __restrict__ offs,
                         const float* __restrict__ mask,
                         const float* __restrict__ w,
                         const float* __restrict__ bias,
                         float* __restrict__ out) {
    // xs tile: [t][ck] bf16, XOR-swizzled cols: col' = col ^ ((t&15)<<3). 49.2 KB.
    // Reused as fp32 obuf[128][OPAD] (33.3 KB) in the epilogue.
    __shared__ ushort xs[TT][CK];

    const int tid  = threadIdx.x;
    const int lane = tid & 63;
    const int wv   = tid >> 6;          // wave 0..3 -> o-rows [wv*32, wv*32+32)
    const int bid  = blockIdx.x;
    const int b    = bid >> 6;          // / NTILE
    const int t0   = (bid & (NTILE - 1)) * TT;

    // ---- A fragments: w[o][ck] -> registers, bf16. Layout (16x16x32):
    // lane holds A[row = lane&15][k = (lane>>4)*8 + j], j=0..7.
    short8 afrag[2][12];
    {
        const int arow = wv * 32 + (lane & 15);
        const int ack  = (lane >> 4) * 8;
#pragma unroll 4
        for (int mf = 0; mf < 2; ++mf) {
            const float* wp = w + (size_t)(arow + mf * 16) * CK + ack;
#pragma unroll 4
            for (int ks = 0; ks < 12; ++ks) {
                floatx4 v0 = *(const floatx4*)(wp + ks * 32);
                floatx4 v1 = *(const floatx4*)(wp + ks * 32 + 4);
                union { uint u[4]; short8 s; } r;
                r.u[0] = (uint)f2bf(v0[0]) | ((uint)f2bf(v0[1]) << 16);
                r.u[1] = (uint)f2bf(v0[2]) | ((uint)f2bf(v0[3]) << 16);
                r.u[2] = (uint)f2bf(v1[0]) | ((uint)f2bf(v1[1]) << 16);
                r.u[3] = (uint)f2bf(v1[2]) | ((uint)f2bf(v1[3]) << 16);
                afrag[mf][ks] = r.s;
            }
        }
    }

    // ---- build xs tile: unit = (t, c-group of 8). 1024 units / 256 threads. ----
    for (int it = 0; it < 4; ++it) {
        const int u  = tid + it * 256;
        const int t  = u & (TT - 1);
        const int cg = u >> 6;                 // 0..15
        const int gt = t0 + t;

        float g0[3], g1[3];
        int   U[3];
#pragma unroll
        for (int k = 0; k < 3; ++k) {
            float ofv = 0.f, mv = 0.f;
            if (gt < LOUT) {
                ofv = offs[((size_t)b * LOUT + gt) * 3 + k];
                mv  = mask[((size_t)b * 3 + k) * LOUT + gt];
            }
            const float gtf = (float)gt;
            float T = (gtf + (float)k) + ofv;          // exact ref op order
            T = fminf(fmaxf(T, gtf), gtf + 2.0f);      // clamp to receptive field
            int Ui = (int)floorf(T);
            if (Ui > LL - 2) Ui = LL - 2;
            const float Uf = (float)Ui;
            g0[k] = fmaxf(0.f, 1.f - fabsf(Uf - T)) * mv;
            g1[k] = fmaxf(0.f, 1.f - fabsf(Uf + 1.f - T)) * mv;
            U[k] = Ui;
        }

        ushort vals[24];
#pragma unroll
        for (int ci = 0; ci < 8; ++ci) {
            const float* xr = x + ((size_t)b * CI + cg * 8 + ci) * LL;
#pragma unroll
            for (int k = 0; k < 3; ++k) {
                const float x0 = xr[U[k]];
                const float x1 = xr[U[k] + 1];         // U <= LL-2 -> in bounds
                vals[ci * 3 + k] = f2bf(g0[k] * x0 + g1[k] * x1);
            }
        }
        uint dw[12];
#pragma unroll
        for (int j = 0; j < 12; ++j)
            dw[j] = (uint)vals[2 * j] | ((uint)vals[2 * j + 1] << 16);
        const int swz = (t & 15) << 3;
#pragma unroll
        for (int j = 0; j < 3; ++j) {
            const int col = (cg * 24 + j * 8) ^ swz;   // 8-aligned, bijective
            uint4 q; q.x = dw[4*j]; q.y = dw[4*j+1]; q.z = dw[4*j+2]; q.w = dw[4*j+3];
            *(uint4*)(&xs[t][col]) = q;
        }
    }
    __syncthreads();

    // ---- GEMM: acc[mf][nf] over 12 k-steps of 32 ----
    floatx4 zero4 = {0.f, 0.f, 0.f, 0.f};
    floatx4 acc[2][4];
#pragma unroll
    for (int mf = 0; mf < 2; ++mf)
#pragma unroll
        for (int nf = 0; nf < 4; ++nf) acc[mf][nf] = zero4;

    const int bswz = (lane & 15) << 3;
#pragma unroll
    for (int ks = 0; ks < 12; ++ks) {
        short8 bfr[4];
#pragma unroll
        for (int nf = 0; nf < 4; ++nf) {
            const int tb  = nf * 16 + (lane & 15);     // B col = lane&15
            const int col = (ks * 32 + (lane >> 4) * 8) ^ bswz;
            bfr[nf] = *(const short8*)(&xs[tb][col]);
        }
#pragma unroll
        for (int mf = 0; mf < 2; ++mf)
#pragma unroll
            for (int nf = 0; nf < 4; ++nf)
                acc[mf][nf] = __builtin_amdgcn_mfma_f32_16x16x32_bf16(
                    afrag[mf][ks], bfr[nf], acc[mf][nf], 0, 0, 0);
    }

    // ---- epilogue: stage D tile in LDS, then aligned float2 row-streaming ----
    // D layout: col(t) = lane&15, row(o) = (lane>>4)*4 + reg.
    __syncthreads();                         // all xs reads done before reuse
    float* obuf = (float*)&xs[0][0];         // [CO][OPAD] = 33.3 KB
#pragma unroll
    for (int mf = 0; mf < 2; ++mf)
#pragma unroll
        for (int nf = 0; nf < 4; ++nf) {
            const int t = nf * 16 + (lane & 15);
#pragma unroll
            for (int r = 0; r < 4; ++r) {
                const int o = wv * 32 + mf * 16 + (lane >> 4) * 4 + r;
                obuf[o * OPAD + t] = acc[mf][nf][r];
            }
        }
    __syncthreads();

    // 4096 float2 = 128 rows x 32; 32 consecutive threads stream one row (256 B).
#pragma unroll 4
    for (int it = 0; it < 16; ++it) {
        const int f  = it * 256 + tid;
        const int o  = f >> 5;
        const int j  = f & 31;
        const int gt = t0 + 2 * j;
        if (gt < LOUT) {                     // LOUT even -> pair fully in-bounds
            const float bv = bias[o];
            float2 v;
            v.x = obuf[o * OPAD + 2 * j]     + bv;
            v.y = obuf[o * OPAD + 2 * j + 1] + bv;
            *(float2*)(out + ((size_t)b * CO + o) * LOUT + gt) = v;   // 8B-aligned
        }
    }
}

extern "C" void kernel_launch(void* const* d_in, const int* in_sizes, int n_in,
                              void* d_out, int out_size, void* d_ws, size_t ws_size,
                              hipStream_t stream) {
    const float* x    = (const float*)d_in[0];
    const float* offs = (const float*)d_in[1];
    const float* mask = (const float*)d_in[2];
    const float* w    = (const float*)d_in[3];
    const float* bias = (const float*)d_in[4];
    float* out = (float*)d_out;

    dim3 grid(BB * NTILE);   // 1024 blocks
    dim3 block(256);
    dconv1d_mfma_kernel<<<grid, block, 0, stream>>>(x, offs, mask, w, bias, out);
}